// Round 6
// baseline (57136.938 us; speedup 1.0000x reference)
//
#include <hip/hip_runtime.h>

// ---------------------------------------------------------------------------
// Seq2seq GRU enc (500) -> local attn -> GRU dec (64). fp32 in/out.
// bf16x3 splits (6-MFMA chains) = fp32-true matmuls; fp64 sig->pt path.
//
// R6: fit ws under R4's proven 224.8MB (no h_trace/gx buffers; in-place encw;
// dec x-part in-loop; outW bf16x1). Hang-proof no-invalidate barrier:
// publish via agent-scope atomic stores (to MALL), spin via atomic fetch_add
// (coherence-point RMW), no buffer_inv -> weights stay L2-resident.
// ---------------------------------------------------------------------------

#define B_    64
#define SRCL  500
#define TRGL  64
#define DIM   512
#define H_    1024
#define WIN   13
#define DW    6

#define EWIHN 1572864   // 3H*DIM
#define EWHHN 3145728   // 3H*H
#define DWIHN 4718592   // 3H*(DIM+H)
#define DWHHN 3145728
#define OUTWN 524288    // DIM*H (bf16x1)
#define OWWN  1048576   // H*H
#define ATWN  1048576
#define BH    (B_ * H_)
#define HN    (2 * BH)  // h plane stride (2 slots)
#define CN    BH
#define FSTR  32        // flag stride in ints (128B)

typedef __attribute__((ext_vector_type(8)))  short short8;
typedef __attribute__((ext_vector_type(16))) float floatx16;

#define MFMA(a, b, c) __builtin_amdgcn_mfma_f32_32x32x16_bf16((a), (b), (c), 0, 0, 0)

__device__ __forceinline__ float bf2f(short s) {
  union { unsigned int u; float f; } v;
  v.u = ((unsigned int)(unsigned short)s) << 16;
  return v.f;
}
__device__ __forceinline__ short f2bf(float f) {
  union { float f; unsigned int u; } v;
  v.f = f;
  unsigned int u = v.u;
  u = (u + 0x7fffu + ((u >> 16) & 1u)) >> 16;  // RNE
  return (short)u;
}
__device__ __forceinline__ floatx16 zero16() {
  floatx16 z;
#pragma unroll
  for (int i = 0; i < 16; ++i) z[i] = 0.f;
  return z;
}
__device__ __forceinline__ float sigm(float x) { return 1.f / (1.f + expf(-x)); }

// ---- coherence-point accessors (cross-XCD, no cache invalidate) ----
__device__ __forceinline__ unsigned long long cld64(const void* p) {
  return __hip_atomic_load((const unsigned long long*)p, __ATOMIC_RELAXED,
                           __HIP_MEMORY_SCOPE_AGENT);
}
__device__ __forceinline__ void cst64(void* p, unsigned long long v) {
  __hip_atomic_store((unsigned long long*)p, v, __ATOMIC_RELAXED,
                     __HIP_MEMORY_SCOPE_AGENT);
}
__device__ __forceinline__ short8 cload16(const short* p) {
  union { unsigned long long u[2]; short8 s; } v;
  v.u[0] = cld64(p);
  v.u[1] = cld64(p + 4);
  return v.s;
}
__device__ __forceinline__ double cloadd(const double* p) {
  union { unsigned long long u; double d; } v;
  v.u = cld64(p);
  return v.d;
}
__device__ __forceinline__ float2 cloadf2(const float* p) {
  union { unsigned long long u; float f[2]; } v;
  v.u = cld64(p);
  return make_float2(v.f[0], v.f[1]);
}
__device__ __forceinline__ void pub4(short* p, short a, short b, short c,
                                     short d) {
  union { unsigned long long u; short s[4]; } pk;
  pk.s[0] = a; pk.s[1] = b; pk.s[2] = c; pk.s[3] = d;
  cst64(p, pk.u);
}
__device__ __forceinline__ void pubf2(float* p, float x, float y) {
  union { unsigned long long u; float f[2]; } pk;
  pk.f[0] = x; pk.f[1] = y;
  cst64(p, pk.u);
}
__device__ __forceinline__ void pubd(double* p, double d) {
  union { unsigned long long u; double dd; } pk;
  pk.dd = d;
  cst64(p, pk.u);
}

// 8 fp32 -> 3 bf16 planes in registers
__device__ __forceinline__ void split8(const float* p, short8& a0, short8& a1,
                                       short8& a2) {
#pragma unroll
  for (int j = 0; j < 8; ++j) {
    float v = p[j];
    short s0 = f2bf(v);
    float r = v - bf2f(s0);
    short s1 = f2bf(r);
    r -= bf2f(s1);
    a0[j] = s0; a1[j] = s1; a2[j] = f2bf(r);
  }
}

#define DECL6(P) floatx16 P##00 = zero16(), P##01 = zero16(), \
                          P##10 = zero16(), P##2 = zero16();
#define SUM6(P, r) (P##00[r] + P##01[r] + P##10[r] + P##2[r])

// coherent A loads — cross-WG dynamic data (h, c planes)
#define LOADA_C(a0v, a1v, a2v, ap, AN, kc)                                    \
  const short8 a0v = cload16((ap) + (size_t)(kc)*16);                         \
  const short8 a1v = cload16((ap) + (size_t)(AN) + (size_t)(kc)*16);          \
  const short8 a2v = cload16((ap) + 2*(size_t)(AN) + (size_t)(kc)*16);

#define CHUNK6(P, a0v, a1v, a2v, bp, BN, kc)                                  \
  {                                                                           \
    const short8 b0v = *(const short8*)((bp) + (size_t)(kc)*16);              \
    const short8 b1v = *(const short8*)((bp) + (size_t)(BN) + (size_t)(kc)*16); \
    const short8 b2v = *(const short8*)((bp) + 2*(size_t)(BN) + (size_t)(kc)*16); \
    P##00 = MFMA(a0v, b0v, P##00);                                            \
    P##01 = MFMA(a0v, b1v, P##01);                                            \
    P##10 = MFMA(a1v, b0v, P##10);                                            \
    P##2  = MFMA(a0v, b2v, P##2);                                             \
    P##2  = MFMA(a1v, b1v, P##2);                                             \
    P##2  = MFMA(a2v, b0v, P##2);                                             \
  }

// C-fragment scatter: row=(r&3)+8*(r>>2)+4*(lane>>5), col=ra
#define WRITE_TILE(dst, EXPR)                                        \
  do {                                                               \
    _Pragma("unroll") for (int r = 0; r < 16; ++r) {                 \
      int row_ = (r & 3) + 8 * (r >> 2) + 4 * (lane >> 5);           \
      (dst)[row_ * 32 + ra] = (EXPR);                                \
    }                                                                \
  } while (0)

// Barrier among 32 WGs of one group. No cache invalidate anywhere: published
// data goes out via agent-scope atomic stores; spin uses fetch_add(0) which
// executes at the coherence point (always fresh).
__device__ __forceinline__ void group_barrier(int* flags, int group_base,
                                              int my_wg, int epoch, int tid) {
  __syncthreads();  // each wave drains its vm ops (incl. atomic stores)
  if (tid == 0)
    __hip_atomic_store(&flags[my_wg * FSTR], epoch, __ATOMIC_RELEASE,
                       __HIP_MEMORY_SCOPE_AGENT);
  if (tid < 32) {
    const int idx = (group_base + tid) * FSTR;
    while (__hip_atomic_fetch_add(&flags[idx], 0, __ATOMIC_RELAXED,
                                  __HIP_MEMORY_SCOPE_AGENT) < epoch)
      __builtin_amdgcn_s_sleep(4);
  }
  __syncthreads();
  asm volatile("" ::: "memory");
}

// fp32 -> 3 bf16 planes (weights, once per launch)
__global__ void split3_kernel(const float* __restrict__ in,
                              short* __restrict__ out, int n) {
  const int i = blockIdx.x * 256 + threadIdx.x;
  if (i >= n) return;
  float v = in[i];
  short s0 = f2bf(v);
  float r = v - bf2f(s0);
  short s1 = f2bf(r);
  r -= bf2f(s1);
  out[i] = s0;
  out[n + i] = s1;
  out[2 * n + i] = f2bf(r);
}
// fp32 -> 1 bf16 plane (outW: terminal output only)
__global__ void split1_kernel(const float* __restrict__ in,
                              short* __restrict__ out, int n) {
  const int i = blockIdx.x * 256 + threadIdx.x;
  if (i < n) out[i] = f2bf(in[i]);
}

// ---------------------------------------------------------------------------
// Encoder: 500 GRU steps; writes fp32 h-trace into enc_w buffer.
// ---------------------------------------------------------------------------
__global__ __launch_bounds__(192) void enc_kernel(
    const float* __restrict__ src, const short* __restrict__ Wih,
    const short* __restrict__ Whh, const float* __restrict__ bih,
    const float* __restrict__ bhh, float* __restrict__ h_f32,
    short* __restrict__ h_pl, float* __restrict__ h_trace,
    int* __restrict__ flags) {
  const int tid  = threadIdx.x;
  const int lane = tid & 63;
  const int wid  = tid >> 6;       // gate 0..2
  const int m    = blockIdx.x >> 5;
  const int js   = blockIdx.x & 31;
  const int ra   = lane & 31;
  const int koff = (lane >> 5) * 8;

  __shared__ float lds[4][1024];

  const int nrow = wid * H_ + js * 32 + ra;
  const short* wih_p = Wih + (size_t)nrow * DIM + koff;
  const short* whh_p = Whh + (size_t)nrow * H_ + koff;
  const float* src_p = src + (size_t)(m * 32 + ra) * (SRCL * DIM) + koff;
  const int hrow = (m * 32 + ra) * H_;

  const int group_base = m * 32;
  const int my_wg = blockIdx.x;

  for (int t = 0; t < SRCL; ++t) {
    const short* hp = h_pl + (t & 1) * BH + hrow + koff;
    DECL6(qi); DECL6(qh);
    {
      const float* xp = src_p + (size_t)t * DIM;
#pragma unroll 4
      for (int kc = 0; kc < DIM / 16; ++kc) {
        short8 a0v, a1v, a2v;
        split8(xp + kc * 16, a0v, a1v, a2v);
        CHUNK6(qi, a0v, a1v, a2v, wih_p, EWIHN, kc);
      }
    }
#pragma unroll 4
    for (int kc = 0; kc < H_ / 16; ++kc) {
      LOADA_C(a0v, a1v, a2v, hp, HN, kc);
      CHUNK6(qh, a0v, a1v, a2v, whh_p, EWHHN, kc);
    }
    if (wid < 2) {
      WRITE_TILE(lds[wid], SUM6(qi, r) + SUM6(qh, r));
    } else {
      WRITE_TILE(lds[2], SUM6(qi, r));
      WRITE_TILE(lds[3], SUM6(qh, r));
    }
    __syncthreads();

    if (tid < 128) {
      const int idx8 = tid * 8;
      const int bl = idx8 >> 5, j0 = idx8 & 31;
      const int bg = m * 32 + bl;
      const int jgb = js * 32 + j0;
      float hn8[8];
      short s08[8], s18[8], s28[8];
#pragma unroll
      for (int k = 0; k < 8; ++k) {
        const int idx = idx8 + k, jg = jgb + k;
        float pr   = lds[0][idx] + bih[jg] + bhh[jg];
        float pz   = lds[1][idx] + bih[H_ + jg] + bhh[H_ + jg];
        float gi_n = lds[2][idx] + bih[2 * H_ + jg];
        float gh_n = lds[3][idx] + bhh[2 * H_ + jg];
        float r_ = sigm(pr), z_ = sigm(pz);
        float n_ = tanhf(gi_n + r_ * gh_n);
        float ho = h_f32[bg * H_ + jg];
        float hn = (1.f - z_) * n_ + z_ * ho;
        h_f32[bg * H_ + jg] = hn;   // own-WG only in enc: plain
        hn8[k] = hn;
        short s0 = f2bf(hn);
        float rr = hn - bf2f(s0);
        short s1 = f2bf(rr);
        s08[k] = s0; s18[k] = s1; s28[k] = f2bf(rr - bf2f(s1));
      }
      short* h0w = h_pl + ((t + 1) & 1) * BH + bg * H_ + jgb;
      pub4(h0w,          s08[0], s08[1], s08[2], s08[3]);
      pub4(h0w + 4,      s08[4], s08[5], s08[6], s08[7]);
      pub4(h0w + HN,     s18[0], s18[1], s18[2], s18[3]);
      pub4(h0w + HN + 4, s18[4], s18[5], s18[6], s18[7]);
      pub4(h0w + 2*HN,     s28[0], s28[1], s28[2], s28[3]);
      pub4(h0w + 2*HN + 4, s28[4], s28[5], s28[6], s28[7]);
      float* htr = h_trace + ((size_t)bg * SRCL + t) * H_ + jgb;
      *(float4*)htr       = make_float4(hn8[0], hn8[1], hn8[2], hn8[3]);
      *(float4*)(htr + 4) = make_float4(hn8[4], hn8[5], hn8[6], hn8[7]);
    }
    group_barrier(flags, group_base, my_wg, t + 1, tid);
  }
}

// ---------------------------------------------------------------------------
// In-place: buf (fp32 h rows) -> buf = buf @ attn_W.T + attn_b.
// 1 WG = one exclusive 32-row stripe; all reads into regs, sync, overwrite.
// ---------------------------------------------------------------------------
__global__ __launch_bounds__(512) void encw_kernel(
    float* __restrict__ buf, const short* __restrict__ attnW,
    const float* __restrict__ attn_b) {
  const int tid  = threadIdx.x;
  const int lane = tid & 63;
  const int wid  = tid >> 6;       // 0..7
  const int ra   = lane & 31;
  const int koff = (lane >> 5) * 8;
  float* Abase = buf + (size_t)blockIdx.x * 32 * H_;
  const float* ap = Abase + (size_t)ra * H_ + koff;

  floatx16 held[4];
#pragma unroll
  for (int i = 0; i < 4; ++i) {
    const int nt = wid * 4 + i;
    const short* bp = attnW + (size_t)(nt * 32 + ra) * H_ + koff;
    DECL6(q);
#pragma unroll 2
    for (int kc = 0; kc < H_ / 16; ++kc) {
      short8 a0v, a1v, a2v;
      split8(ap + kc * 16, a0v, a1v, a2v);
      CHUNK6(q, a0v, a1v, a2v, bp, ATWN, kc);
    }
#pragma unroll
    for (int r = 0; r < 16; ++r) held[i][r] = SUM6(q, r);
  }
  __syncthreads();  // every wave's A reads retired before overwrite
#pragma unroll
  for (int i = 0; i < 4; ++i) {
    const int nt = wid * 4 + i;
    const float bias = attn_b[nt * 32 + ra];
#pragma unroll
    for (int r = 0; r < 16; ++r) {
      const int row = (r & 3) + 8 * (r >> 2) + 4 * (lane >> 5);
      Abase[(size_t)row * H_ + nt * 32 + ra] = held[i][r] + bias;
    }
  }
}

// ---------------------------------------------------------------------------
// Decoder: 64 steps, 3 phases. x-part in-loop (K=512 over trg).
// ---------------------------------------------------------------------------
__global__ __launch_bounds__(192) void dec_kernel(
    const float* __restrict__ trg, const short* __restrict__ Wih,
    const short* __restrict__ Whh, const float* __restrict__ bih,
    const float* __restrict__ bhh, const short* __restrict__ outW,
    const float* __restrict__ outb, const short* __restrict__ owW,
    const float* __restrict__ owb, const float* __restrict__ ovW,
    const float* __restrict__ ovb, const float* __restrict__ enc_w,
    float* __restrict__ h_f32, short* __restrict__ h_pl,
    short* __restrict__ c_pl, double* __restrict__ sig_part,
    int* __restrict__ flags, float* __restrict__ out) {
  const int tid  = threadIdx.x;
  const int lane = tid & 63;
  const int wid  = tid >> 6;
  const int m    = blockIdx.x >> 5;
  const int js   = blockIdx.x & 31;
  const int ra   = lane & 31;
  const int koff = (lane >> 5) * 8;

  __shared__ float lds[4][1024];
  __shared__ float al13[WIN];
  __shared__ float ah13[WIN];

  const int nrow = wid * H_ + js * 32 + ra;
  const short* wx_p = Wih + (size_t)nrow * (DIM + H_) + koff;  // x cols
  const short* wc_p = wx_p + DIM;                              // c cols
  const short* wh_p = Whh + (size_t)nrow * H_ + koff;
  const float* trg_p = trg + (size_t)(m * 32 + ra) * (TRGL * DIM) + koff;
  const int hrow = (m * 32 + ra) * H_;
  const short* cp = c_pl + hrow + koff;
  const short* ow_p = owW + (size_t)(js * 32 + ra) * H_ + koff;
  const short* outw_p = outW + (size_t)((js & 15) * 32 + ra) * H_ + koff;

  const int group_base = m * 32;
  const int my_wg = blockIdx.x;
  const int b3 = blockIdx.x;  // P3: WG <-> batch

  for (int t = 0; t < TRGL; ++t) {
    const int rd = t & 1, wr = (t + 1) & 1;
    const short* hp = h_pl + rd * BH + hrow + koff;

    // ---- P1: gi = x@Wx + c@Wc ; gh = h@Whh ----
    DECL6(qi); DECL6(qh);
    if (t > 0) {
      const float* xp = trg_p + (size_t)(t - 1) * DIM;
#pragma unroll 4
      for (int kc = 0; kc < DIM / 16; ++kc) {
        short8 a0v, a1v, a2v;
        split8(xp + kc * 16, a0v, a1v, a2v);
        CHUNK6(qi, a0v, a1v, a2v, wx_p, DWIHN, kc);
      }
    }
#pragma unroll 4
    for (int kc = 0; kc < H_ / 16; ++kc) {
      LOADA_C(a0v, a1v, a2v, cp, CN, kc);
      CHUNK6(qi, a0v, a1v, a2v, wc_p, DWIHN, kc);
    }
#pragma unroll 4
    for (int kc = 0; kc < H_ / 16; ++kc) {
      LOADA_C(a0v, a1v, a2v, hp, HN, kc);
      CHUNK6(qh, a0v, a1v, a2v, wh_p, DWHHN, kc);
    }
    if (wid < 2) {
      WRITE_TILE(lds[wid], SUM6(qi, r) + SUM6(qh, r));
    } else {
      WRITE_TILE(lds[2], SUM6(qi, r));
      WRITE_TILE(lds[3], SUM6(qh, r));
    }
    __syncthreads();
    if (tid < 128) {
      const int idx8 = tid * 8;
      const int bl = idx8 >> 5, j0 = idx8 & 31;
      const int bg = m * 32 + bl;
      const int jgb = js * 32 + j0;
      float hn8[8];
      short s08[8], s18[8], s28[8];
#pragma unroll
      for (int k = 0; k < 8; ++k) {
        const int idx = idx8 + k, jg = jgb + k;
        float pr   = lds[0][idx] + bih[jg] + bhh[jg];
        float pz   = lds[1][idx] + bih[H_ + jg] + bhh[H_ + jg];
        float gi_n = lds[2][idx] + bih[2 * H_ + jg];
        float gh_n = lds[3][idx] + bhh[2 * H_ + jg];
        float r_ = sigm(pr), z_ = sigm(pz);
        float n_ = tanhf(gi_n + r_ * gh_n);
        float ho = h_f32[bg * H_ + jg];
        float hn = (1.f - z_) * n_ + z_ * ho;
        hn8[k] = hn;
        short s0 = f2bf(hn);
        float rr = hn - bf2f(s0);
        short s1 = f2bf(rr);
        s08[k] = s0; s18[k] = s1; s28[k] = f2bf(rr - bf2f(s1));
      }
      float* hf = h_f32 + bg * H_ + jgb;
      pubf2(hf,     hn8[0], hn8[1]); pubf2(hf + 2, hn8[2], hn8[3]);
      pubf2(hf + 4, hn8[4], hn8[5]); pubf2(hf + 6, hn8[6], hn8[7]);
      short* h0w = h_pl + wr * BH + bg * H_ + jgb;
      pub4(h0w,          s08[0], s08[1], s08[2], s08[3]);
      pub4(h0w + 4,      s08[4], s08[5], s08[6], s08[7]);
      pub4(h0w + HN,     s18[0], s18[1], s18[2], s18[3]);
      pub4(h0w + HN + 4, s18[4], s18[5], s18[6], s18[7]);
      pub4(h0w + 2*HN,     s28[0], s28[1], s28[2], s28[3]);
      pub4(h0w + 2*HN + 4, s28[4], s28[5], s28[6], s28[7]);
    }
    group_barrier(flags, group_base, my_wg, 3 * t + 1, tid);

    // ---- P2: T = tanh(h@owW.T + owb); sig partials (fp64); y ----
    const short* hc = h_pl + wr * BH + hrow + koff;
    {
      DECL6(qt);
      for (int kc = wid; kc < H_ / 16; kc += 3) {
        LOADA_C(a0v, a1v, a2v, hc, HN, kc);
        CHUNK6(qt, a0v, a1v, a2v, ow_p, OWWN, kc);
      }
      WRITE_TILE(lds[wid], SUM6(qt, r));
    }
    __syncthreads();
    for (int idx = tid; idx < 1024; idx += 192) {
      float s3 = lds[0][idx] + lds[1][idx] + lds[2][idx] +
                 owb[js * 32 + (idx & 31)];
      lds[0][idx] = tanhf(s3);
    }
    __syncthreads();
    if (tid < 32) {
      double sv = 0.0;
#pragma unroll 8
      for (int j = 0; j < 32; ++j)
        sv += (double)lds[0][tid * 32 + j] * (double)ovW[js * 32 + j];
      pubd(&sig_part[(size_t)(t * 32 + js) * B_ + m * 32 + tid], sv);
    }
    __syncthreads();
    if (js < 16) {
      floatx16 y0 = zero16(), y1 = zero16();
      for (int kc = wid; kc < H_ / 16; kc += 3) {
        LOADA_C(a0v, a1v, a2v, hc, HN, kc);
        const short8 b0v = *(const short8*)(outw_p + (size_t)kc * 16);
        y0 = MFMA(a0v, b0v, y0);
        y1 = MFMA(a1v, b0v, y1);
        (void)a2v;
      }
      WRITE_TILE(lds[wid], y0[r] + y1[r]);
    }
    __syncthreads();
    if (js < 16) {
      for (int idx = tid; idx < 1024; idx += 192) {
        const int bl = idx >> 5, j = idx & 31;
        const int d = js * 32 + j;
        float v = lds[0][idx] + lds[1][idx] + lds[2][idx] + outb[d];
        out[(size_t)(m * 32 + bl) * (TRGL * DIM) + (size_t)t * DIM + d] = v;
      }
    }
    group_barrier(flags, group_base, my_wg, 3 * t + 2, tid);

    // ---- P3: pt (fp64), alpha, context (one WG per batch) ----
    {
      double sigv = (double)ovb[0];
      for (int p = 0; p < 32; ++p)  // fixed order: deterministic
        sigv += cloadd(&sig_part[(size_t)(t * 32 + p) * B_ + b3]);
      const double ptv = 487.0 / (1.0 + exp(-sigv)) + 6.0;
      const int center = (int)ptv;  // floor (pt > 0)
      const int row0 = center - DW;
      const float ptf = (float)ptv;
      const float* sv_b = h_f32 + b3 * H_ + lane * 16;
      for (int w = wid; w < WIN; w += 3) {
        const float* ew =
            enc_w + ((size_t)b3 * SRCL + row0 + w) * H_ + lane * 16;
        float part = 0.f;
#pragma unroll
        for (int i = 0; i < 8; ++i) {
          float2 s2 = cloadf2(sv_b + 2 * i);
          part += ew[2 * i] * s2.x + ew[2 * i + 1] * s2.y;
        }
#pragma unroll
        for (int off = 32; off; off >>= 1) part += __shfl_xor(part, off, 64);
        if (lane == 0) ah13[w] = part;
      }
      __syncthreads();
      if (tid == 0) {
        float v[WIN], mx = -1e30f;
#pragma unroll
        for (int w = 0; w < WIN; ++w) {
          const float dd = (float)(row0 + w) - ptf;
          v[w] = ah13[w] * expf(-(dd * dd) / 18.f);  // 2*sigma^2 = 18
          mx = fmaxf(mx, v[w]);
        }
        float ssum = 0.f;
#pragma unroll
        for (int w = 0; w < WIN; ++w) { v[w] = expf(v[w] - mx); ssum += v[w]; }
        const float inv = 1.f / ssum;
#pragma unroll
        for (int w = 0; w < WIN; ++w) al13[w] = v[w] * inv;
      }
      __syncthreads();
      if (tid < 128) {
        const int hh0 = tid * 8;
        float acc[8];
#pragma unroll
        for (int k = 0; k < 8; ++k) acc[k] = 0.f;
        const float* ewb = enc_w + ((size_t)b3 * SRCL + row0) * H_ + hh0;
#pragma unroll
        for (int w = 0; w < WIN; ++w) {
#pragma unroll
          for (int k = 0; k < 8; ++k) acc[k] += al13[w] * ewb[(size_t)w * H_ + k];
        }
        short s08[8], s18[8], s28[8];
#pragma unroll
        for (int k = 0; k < 8; ++k) {
          short s0 = f2bf(acc[k]);
          float rr = acc[k] - bf2f(s0);
          short s1 = f2bf(rr);
          s08[k] = s0; s18[k] = s1; s28[k] = f2bf(rr - bf2f(s1));
        }
        short* cw = c_pl + b3 * H_ + hh0;
        pub4(cw,          s08[0], s08[1], s08[2], s08[3]);
        pub4(cw + 4,      s08[4], s08[5], s08[6], s08[7]);
        pub4(cw + CN,     s18[0], s18[1], s18[2], s18[3]);
        pub4(cw + CN + 4, s18[4], s18[5], s18[6], s18[7]);
        pub4(cw + 2*CN,     s28[0], s28[1], s28[2], s28[3]);
        pub4(cw + 2*CN + 4, s28[4], s28[5], s28[6], s28[7]);
      }
    }
    group_barrier(flags, group_base, my_wg, 3 * t + 3, tid);
  }
}

extern "C" void kernel_launch(void* const* d_in, const int* in_sizes, int n_in,
                              void* d_out, int out_size, void* d_ws,
                              size_t ws_size, hipStream_t stream) {
  (void)in_sizes; (void)n_in; (void)out_size; (void)ws_size;

  const float* src     = (const float*)d_in[0];
  const float* trg     = (const float*)d_in[1];
  const float* enc_Wih = (const float*)d_in[2];
  const float* enc_Whh = (const float*)d_in[3];
  const float* enc_bih = (const float*)d_in[4];
  const float* enc_bhh = (const float*)d_in[5];
  const float* dec_Wih = (const float*)d_in[6];
  const float* dec_Whh = (const float*)d_in[7];
  const float* dec_bih = (const float*)d_in[8];
  const float* dec_bhh = (const float*)d_in[9];
  const float* out_W   = (const float*)d_in[10];
  const float* out_b   = (const float*)d_in[11];
  const float* ow_W    = (const float*)d_in[12];
  const float* ow_b    = (const float*)d_in[13];
  const float* ov_W    = (const float*)d_in[14];
  const float* ov_b    = (const float*)d_in[15];
  const float* attn_W  = (const float*)d_in[16];
  const float* attn_b  = (const float*)d_in[17];

  char* ws = (char*)d_ws;
  size_t off = 0;
  auto take = [&](size_t bytes) {
    size_t o = off;
    off += (bytes + 255) & ~(size_t)255;
    return o;
  };

  // --- zeroed state region ---
  float* h_f32   = (float*)(ws + take(BH * 4));
  short* h_pl    = (short*)(ws + take((size_t)3 * HN * 2));
  short* c_pl    = (short*)(ws + take((size_t)3 * CN * 2));
  int*   flags_e = (int*)(ws + take(64 * FSTR * 4));
  int*   flags_d = (int*)(ws + take(64 * FSTR * 4));
  const size_t zero_bytes = off;

  // --- non-zeroed (total ws ~222.7MB, under R4-proven 224.8MB) ---
  double* sig_part = (double*)(ws + take((size_t)TRGL * 32 * B_ * 8));
  short* pWihE = (short*)(ws + take((size_t)3 * EWIHN * 2));
  short* pWhhE = (short*)(ws + take((size_t)3 * EWHHN * 2));
  short* pWihD = (short*)(ws + take((size_t)3 * DWIHN * 2));
  short* pWhhD = (short*)(ws + take((size_t)3 * DWHHN * 2));
  short* pOwW  = (short*)(ws + take((size_t)3 * OWWN * 2));
  short* pOutW = (short*)(ws + take((size_t)OUTWN * 2));      // bf16x1
  short* pAtW  = (short*)(ws + take((size_t)3 * ATWN * 2));
  float* enc_w = (float*)(ws + take((size_t)B_ * SRCL * H_ * 4));  // 131MB

  hipMemsetAsync(ws, 0, zero_bytes, stream);

  auto split = [&](const float* in, short* outp, int n) {
    split3_kernel<<<dim3((n + 255) / 256), dim3(256), 0, stream>>>(in, outp, n);
  };
  split(enc_Wih, pWihE, EWIHN);
  split(enc_Whh, pWhhE, EWHHN);
  split(dec_Wih, pWihD, DWIHN);
  split(dec_Whh, pWhhD, DWHHN);
  split(ow_W,   pOwW,  OWWN);
  split(attn_W, pAtW,  ATWN);
  split1_kernel<<<dim3((OUTWN + 255) / 256), dim3(256), 0, stream>>>(
      out_W, pOutW, OUTWN);

  // enc writes fp32 h-trace into enc_w buffer
  enc_kernel<<<dim3(64), dim3(192), 0, stream>>>(
      src, pWihE, pWhhE, enc_bih, enc_bhh, h_f32, h_pl, enc_w, flags_e);

  // in-place: enc_w = h_trace @ attn_W.T + attn_b
  encw_kernel<<<dim3(1000), dim3(512), 0, stream>>>(enc_w, pAtW, attn_b);

  dec_kernel<<<dim3(64), dim3(192), 0, stream>>>(
      trg, pWihD, pWhhD, dec_bih, dec_bhh, pOutW, out_b, pOwW, ow_b, ov_W,
      ov_b, enc_w, h_f32, h_pl, c_pl, sig_part, flags_d, (float*)d_out);
}